// Round 7
// baseline (444.385 us; speedup 1.0000x reference)
//
#include <hip/hip_runtime.h>
#include <math.h>

#define BB   16
#define CC   512
#define HWW  576
#define NN   9216            // B*HW
#define CHW  (CC*HWW)        // 294912
#define TOT  (BB*CHW)        // 4718592
#define SCALE 0.044194173824159216f  // 1/sqrt(512)
#define FRAGB 9437184        // NN*CC bf16 bytes

typedef __attribute__((ext_vector_type(8))) __bf16 bf16x8;
typedef __attribute__((ext_vector_type(4))) float f32x4;

#define AS1 __attribute__((address_space(1)))
#define AS3 __attribute__((address_space(3)))

// async 16B global->LDS: lds dest = wave-uniform base + lane*16
static __device__ __forceinline__ void gload_lds16(const void* g, void* l)
{
    __builtin_amdgcn_global_load_lds((AS1 const void*)g, (AS3 void*)l, 16, 0, 0);
}

// ---------------------------------------------------------------------------
// Fragment-linear bf16 layout (MFMA A/B operand order), 64x64 (dim,k) blocks:
//   slot(elem) = (s*4+g4)*512 + L*8 + j,  L = (q8<<4)|Lm
//   dim64 = g4*16 + Lm,   k64 = s*32 + q8*8 + j
// X/x5/q/k ("B-side", dim=pixel, k=channel): block index [Cb*144 + T]
// W ("A-side", dim=out-chan, k=in-chan):     block index [Cb*8  + To]
// Frag read for mfma_16x16x32_bf16: contiguous 16 B at lane*16.
// ---------------------------------------------------------------------------

// P1: x -> hi/lo bf16 fragment layout
__global__ __launch_bounds__(256)
void prep_x_kernel(const float* __restrict__ X, __bf16* __restrict__ Xhi,
                   __bf16* __restrict__ Xlo)
{
    int g = blockIdx.x * 256 + threadIdx.x;   // NN*64 threads
    int n = g % NN;
    int co = g / NN;                          // channel octet 0..63
    int c0 = co * 8;
    int bimg = n / HWW, mm = n % HWW;
    const float* src = X + (size_t)bimg * CHW + mm;
    union { __bf16 h[8]; float4 f4; } uh, ul;
#pragma unroll
    for (int j = 0; j < 8; j++) {
        float v = src[(size_t)(c0 + j) * HWW];
        __bf16 h = (__bf16)v;
        uh.h[j] = h;
        ul.h[j] = (__bf16)(v - (float)h);
    }
    int Cb = c0 >> 6, s = (c0 >> 5) & 1, q8 = (c0 >> 3) & 3;
    int T = n >> 6, g4 = (n >> 4) & 3, Lm = n & 15;
    size_t off = (size_t)(Cb * 144 + T) * 4096 + (s * 4 + g4) * 512 + (size_t)((q8 << 4) | Lm) * 8;
    *(float4*)&Xhi[off] = uh.f4;
    *(float4*)&Xlo[off] = ul.f4;
}

// P2: weights -> fragment layout. y=0: cw (hi+lo), y=1: qw, y=2: kw
__global__ __launch_bounds__(256)
void prep_w_kernel(const float* __restrict__ cw, const float* __restrict__ qw,
                   const float* __restrict__ kw, __bf16* __restrict__ cwhi,
                   __bf16* __restrict__ cwlo, __bf16* __restrict__ qwf,
                   __bf16* __restrict__ kwf)
{
    int y = blockIdx.y;
    const float* W = (y == 0) ? cw : (y == 1) ? qw : kw;
    __bf16* dh = (y == 0) ? cwhi : (y == 1) ? qwf : kwf;
    int g = blockIdx.x * 256 + threadIdx.x;   // 512*64 threads
    int o = g >> 6;
    int c0 = (g & 63) * 8;
    union { __bf16 h[8]; float4 f4; } uh, ul;
#pragma unroll
    for (int j = 0; j < 8; j++) {
        float v = W[(size_t)o * CC + c0 + j];
        __bf16 h = (__bf16)v;
        uh.h[j] = h;
        ul.h[j] = (__bf16)(v - (float)h);
    }
    int Cb = c0 >> 6, s = (c0 >> 5) & 1, q8 = (c0 >> 3) & 3;
    int To = o >> 6, g4 = (o >> 4) & 3, Lm = o & 15;
    size_t off = (size_t)(Cb * 8 + To) * 4096 + (s * 4 + g4) * 512 + (size_t)((q8 << 4) | Lm) * 8;
    *(float4*)&dh[off] = uh.f4;
    if (y == 0) *(float4*)&cwlo[off] = ul.f4;
}

// ---------------------------------------------------------------------------
// K1: x5 conv via hi/lo bf16 MFMA + residual + bias.
// A-side (weights) frags read DIRECTLY from global (L2-hot, contiguous
// lane*16) -> LDS only stages B (32 KB) -> 4-5 blocks/CU (was 2 at 64 KB).
// ---------------------------------------------------------------------------
__global__ __launch_bounds__(256)
void conv1_mfma_kernel(const float* __restrict__ X, const __bf16* __restrict__ Whi,
                       const __bf16* __restrict__ Wlo, const __bf16* __restrict__ Xhi,
                       const __bf16* __restrict__ Xlo, const float* __restrict__ bias,
                       float* __restrict__ Y, __bf16* __restrict__ Yfrag)
{
    __shared__ __bf16 lBh[8192], lBl[8192];
    int tid = threadIdx.x, lane = tid & 63, wv = tid >> 6;
    int wo = wv >> 1, wm = wv & 1;
    int m0 = blockIdx.x * 128;
    int o0 = blockIdx.y * 128;
    int oT0 = blockIdx.y * 2, mT0 = blockIdx.x * 2;

    f32x4 acc[4][4];
#pragma unroll
    for (int i = 0; i < 4; i++)
#pragma unroll
        for (int j = 0; j < 4; j++) acc[i][j] = (f32x4){0.f, 0.f, 0.f, 0.f};

    for (int Cb = 0; Cb < 8; Cb++) {
        const float4* gBh = (const float4*)(Xhi + (size_t)(Cb * 144 + mT0) * 4096);
        const float4* gBl = (const float4*)(Xlo + (size_t)(Cb * 144 + mT0) * 4096);
#pragma unroll
        for (int i = 0; i < 4; i++) {
            int eb = wv * 256 + i * 64;
            gload_lds16(gBh + eb + lane, (float4*)lBh + eb);
            gload_lds16(gBl + eb + lane, (float4*)lBl + eb);
        }
        const __bf16* Ah = Whi + (size_t)(Cb * 8 + oT0 + wo) * 4096 + lane * 8;
        const __bf16* Al = Wlo + (size_t)(Cb * 8 + oT0 + wo) * 4096 + lane * 8;
        __syncthreads();
#pragma unroll
        for (int s = 0; s < 2; s++) {
            bf16x8 ah[4], al[4], bh[4], bl[4];
#pragma unroll
            for (int ga = 0; ga < 4; ga++) {
                ah[ga] = *(const bf16x8*)&Ah[(s * 4 + ga) * 512];
                al[ga] = *(const bf16x8*)&Al[(s * 4 + ga) * 512];
            }
#pragma unroll
            for (int gb = 0; gb < 4; gb++) {
                bh[gb] = *(const bf16x8*)&lBh[wm * 4096 + (s * 4 + gb) * 512 + lane * 8];
                bl[gb] = *(const bf16x8*)&lBl[wm * 4096 + (s * 4 + gb) * 512 + lane * 8];
            }
#pragma unroll
            for (int ga = 0; ga < 4; ga++)
#pragma unroll
                for (int gb = 0; gb < 4; gb++) {
                    acc[ga][gb] = __builtin_amdgcn_mfma_f32_16x16x32_bf16(ah[ga], bh[gb], acc[ga][gb], 0, 0, 0);
                    acc[ga][gb] = __builtin_amdgcn_mfma_f32_16x16x32_bf16(ah[ga], bl[gb], acc[ga][gb], 0, 0, 0);
                    acc[ga][gb] = __builtin_amdgcn_mfma_f32_16x16x32_bf16(al[ga], bh[gb], acc[ga][gb], 0, 0, 0);
                }
        }
        __syncthreads();
    }

    int quad = lane >> 4, col = lane & 15;
#pragma unroll
    for (int ga = 0; ga < 4; ga++) {
        int ob = o0 + wo * 64 + ga * 16 + quad * 4;
        float bs[4];
#pragma unroll
        for (int r = 0; r < 4; r++) bs[r] = bias[ob + r];
        int Cb2 = ob >> 6, s2 = (ob >> 5) & 1, q8 = (ob >> 3) & 3, j0 = ob & 7;
#pragma unroll
        for (int gb = 0; gb < 4; gb++) {
            int n = m0 + wm * 64 + gb * 16 + col;
            int T = n >> 6, g4 = (n >> 4) & 3, Lm = n & 15;
            int bimg = n / HWW, mm = n % HWW;
            size_t xb = (size_t)bimg * CHW + mm;
            union { __bf16 h[4]; float2 f2; } u;
#pragma unroll
            for (int r = 0; r < 4; r++) {
                float v = acc[ga][gb][r] + bs[r] + X[xb + (size_t)(ob + r) * HWW];
                Y[xb + (size_t)(ob + r) * HWW] = v;
                u.h[r] = (__bf16)v;
            }
            *(float2*)&Yfrag[(size_t)(Cb2 * 144 + T) * 4096 + (s2 * 4 + g4) * 512 + (size_t)((q8 << 4) | Lm) * 8 + j0] = u.f2;
        }
    }
}

// ---------------------------------------------------------------------------
// K2: q & k convs, A-side direct from global, B via LDS (16 KB).
// ---------------------------------------------------------------------------
__global__ __launch_bounds__(256)
void convqk_mfma_kernel(const __bf16* __restrict__ qwf, const __bf16* __restrict__ kwf,
                        const float* __restrict__ qb, const float* __restrict__ kb,
                        const __bf16* __restrict__ Xf, __bf16* __restrict__ Oq,
                        __bf16* __restrict__ Ok)
{
    const __bf16* Wf = blockIdx.z ? kwf : qwf;
    const float* bias = blockIdx.z ? kb : qb;
    __bf16* Of = blockIdx.z ? Ok : Oq;

    __shared__ __bf16 lB[8192];
    int tid = threadIdx.x, lane = tid & 63, wv = tid >> 6;
    int wo = wv >> 1, wm = wv & 1;
    int m0 = blockIdx.x * 128;
    int o0 = blockIdx.y * 128;
    int oT0 = blockIdx.y * 2, mT0 = blockIdx.x * 2;

    f32x4 acc[4][4];
#pragma unroll
    for (int i = 0; i < 4; i++)
#pragma unroll
        for (int j = 0; j < 4; j++) acc[i][j] = (f32x4){0.f, 0.f, 0.f, 0.f};

    for (int Cb = 0; Cb < 8; Cb++) {
        const float4* gB = (const float4*)(Xf + (size_t)(Cb * 144 + mT0) * 4096);
#pragma unroll
        for (int i = 0; i < 4; i++) {
            int eb = wv * 256 + i * 64;
            gload_lds16(gB + eb + lane, (float4*)lB + eb);
        }
        const __bf16* Aw = Wf + (size_t)(Cb * 8 + oT0 + wo) * 4096 + lane * 8;
        __syncthreads();
#pragma unroll
        for (int s = 0; s < 2; s++) {
            bf16x8 af[4], bf[4];
#pragma unroll
            for (int ga = 0; ga < 4; ga++)
                af[ga] = *(const bf16x8*)&Aw[(s * 4 + ga) * 512];
#pragma unroll
            for (int gb = 0; gb < 4; gb++)
                bf[gb] = *(const bf16x8*)&lB[wm * 4096 + (s * 4 + gb) * 512 + lane * 8];
#pragma unroll
            for (int ga = 0; ga < 4; ga++)
#pragma unroll
                for (int gb = 0; gb < 4; gb++)
                    acc[ga][gb] = __builtin_amdgcn_mfma_f32_16x16x32_bf16(af[ga], bf[gb], acc[ga][gb], 0, 0, 0);
        }
        __syncthreads();
    }

    int quad = lane >> 4, col = lane & 15;
#pragma unroll
    for (int ga = 0; ga < 4; ga++) {
        int ob = o0 + wo * 64 + ga * 16 + quad * 4;
        float bs[4];
#pragma unroll
        for (int r = 0; r < 4; r++) bs[r] = bias[ob + r];
        int Cb2 = ob >> 6, s2 = (ob >> 5) & 1, q8 = (ob >> 3) & 3, j0 = ob & 7;
#pragma unroll
        for (int gb = 0; gb < 4; gb++) {
            int n = m0 + wm * 64 + gb * 16 + col;
            int T = n >> 6, g4 = (n >> 4) & 3, Lm = n & 15;
            union { __bf16 h[4]; float2 f2; } u;
#pragma unroll
            for (int r = 0; r < 4; r++) u.h[r] = (__bf16)(acc[ga][gb][r] + bs[r]);
            *(float2*)&Of[(size_t)(Cb2 * 144 + T) * 4096 + (s2 * 4 + g4) * 512 + (size_t)((q8 << 4) | Lm) * 8 + j0] = u.f2;
        }
    }
}

// ---------------------------------------------------------------------------
// K4: scores GEMM + max. Block 128q x 192k, wave 64x96, single launch,
// XCD swizzle (bid%48 = k-tile).
// ---------------------------------------------------------------------------
__global__ __launch_bounds__(256)
void scores_mfma_kernel(const __bf16* __restrict__ Qf, const __bf16* __restrict__ Kf,
                        float* __restrict__ maxv3)
{
    __shared__ __bf16 ldsQ[8192];    // 16 KB (redbuf aliases)
    __shared__ __bf16 ldsK[12288];   // 24 KB

    int tid = threadIdx.x, lane = tid & 63, wv = tid >> 6;
    int wq = wv >> 1, wk = wv & 1;
    int bid = blockIdx.x;
    int by = bid % 48;
    int bx = bid / 48;
    int n0 = bx * 128;
    int b = by / 3, mt = by % 3;

    f32x4 acc[4][6];
#pragma unroll
    for (int ga = 0; ga < 4; ga++)
#pragma unroll
        for (int t = 0; t < 6; t++) acc[ga][t] = (f32x4){0.f, 0.f, 0.f, 0.f};

    const float4* gq = (const float4*)(Qf + (size_t)(bx * 2) * 4096);
    const float4* gk = (const float4*)(Kf + (size_t)(b * 9 + mt * 3) * 4096);
    const int CSTRIDE = 144 * 4096 / 8;

    for (int C = 0; C < 8; C++) {
#pragma unroll
        for (int i = 0; i < 4; i++) {
            int eb = wv * 256 + i * 64;
            gload_lds16(gq + eb + lane, (float4*)ldsQ + eb);
        }
#pragma unroll
        for (int i = 0; i < 6; i++) {
            int eb = wv * 384 + i * 64;
            gload_lds16(gk + eb + lane, (float4*)ldsK + eb);
        }
        gq += CSTRIDE;
        gk += CSTRIDE;
        __syncthreads();
#pragma unroll
        for (int s = 0; s < 2; s++) {
            bf16x8 af[4];
#pragma unroll
            for (int ga = 0; ga < 4; ga++)
                af[ga] = *(const bf16x8*)&ldsQ[wq * 4096 + (s * 4 + ga) * 512 + lane * 8];
#pragma unroll
            for (int t = 0; t < 6; t++) {
                int mkl = wk * 96 + t * 16;
                bf16x8 bfr = *(const bf16x8*)&ldsK[(mkl >> 6) * 4096 + (s * 4 + ((mkl >> 4) & 3)) * 512 + lane * 8];
#pragma unroll
                for (int ga = 0; ga < 4; ga++)
                    acc[ga][t] = __builtin_amdgcn_mfma_f32_16x16x32_bf16(af[ga], bfr, acc[ga][t], 0, 0, 0);
            }
        }
        __syncthreads();
    }

    float mg[4][4];
#pragma unroll
    for (int ga = 0; ga < 4; ga++)
#pragma unroll
        for (int r = 0; r < 4; r++) {
            float v = acc[ga][0][r];
#pragma unroll
            for (int t = 1; t < 6; t++) v = fmaxf(v, acc[ga][t][r]);
            mg[ga][r] = v;
        }
#pragma unroll
    for (int off = 1; off < 16; off <<= 1)
#pragma unroll
        for (int ga = 0; ga < 4; ga++)
#pragma unroll
            for (int r = 0; r < 4; r++)
                mg[ga][r] = fmaxf(mg[ga][r], __shfl_xor(mg[ga][r], off, 64));

    float (*redbuf)[2] = (float (*)[2])ldsQ;
    if ((lane & 15) == 0) {
        int quad = lane >> 4;
#pragma unroll
        for (int ga = 0; ga < 4; ga++)
#pragma unroll
            for (int r = 0; r < 4; r++)
                redbuf[wq * 64 + ga * 16 + quad * 4 + r][wk] = mg[ga][r];
    }
    __syncthreads();
    if (tid < 128) {
        float rv = fmaxf(redbuf[tid][0], redbuf[tid][1]) * SCALE;
        maxv3[((size_t)(n0 + tid) * BB + b) * 3 + mt] = rv;
    }
}

// ---------------------------------------------------------------------------
// K5: approx v, top-4 candidates per image.
// ---------------------------------------------------------------------------
__global__ __launch_bounds__(576)
void topk_kernel(const float* __restrict__ maxv3, int* __restrict__ cand)
{
    __shared__ float sv[576];
    __shared__ float rv_[64];
    __shared__ int ri_[64];
    int bi = blockIdx.x, m = threadIdx.x;
    int n = bi * HWW + m;
    float v = 0.f;
#pragma unroll
    for (int t = 0; t < BB; t++) {
        const float* p = maxv3 + ((size_t)n * BB + t) * 3;
        v += fmaxf(fmaxf(p[0], p[1]), p[2]);
    }
    sv[m] = v;
    __syncthreads();
    for (int r = 0; r < 4; r++) {
        if (m < 64) {
            float bv = sv[m]; int bidx = m;
            for (int j = m + 64; j < 576; j += 64)
                if (sv[j] > bv) { bv = sv[j]; bidx = j; }
            rv_[m] = bv; ri_[m] = bidx;
        }
        __syncthreads();
        if (m == 0) {
            float bv = rv_[0]; int bidx = ri_[0];
            for (int j = 1; j < 64; j++)
                if (rv_[j] > bv) { bv = rv_[j]; bidx = ri_[j]; }
            cand[bi * 4 + r] = bidx;
            sv[bidx] = -3.4e38f;
        }
        __syncthreads();
    }
}

// ---------------------------------------------------------------------------
// K6: fused exact refinement: q = Qw*xcol+qb (in LDS), u = Kw^T q, qkb.
// One block per candidate (64 blocks).
// ---------------------------------------------------------------------------
__global__ __launch_bounds__(256)
void refine_qu_kernel(const float* __restrict__ x5, const float* __restrict__ qw,
                      const float* __restrict__ qb, const float* __restrict__ kw,
                      const float* __restrict__ kb, const int* __restrict__ cand,
                      float* __restrict__ u_all, float* __restrict__ qkbg)
{
    int cd = blockIdx.x;
    int bi = cd >> 2;
    int mstar = cand[cd];
    int tid = threadIdx.x, w = tid >> 6, lane = tid & 63;
    __shared__ float xcol[512], qv[512];
    xcol[tid]       = x5[(size_t)bi * CHW + tid * HWW + mstar];
    xcol[tid + 256] = x5[(size_t)bi * CHW + (tid + 256) * HWW + mstar];
    __syncthreads();
    for (int i = 0; i < 128; i++) {
        int r = w * 128 + i;
        float p = 0.f;
#pragma unroll
        for (int it = 0; it < 8; it++) {
            int c = lane + it * 64;
            p = fmaf(qw[(size_t)r * 512 + c], xcol[c], p);
        }
        for (int off = 32; off; off >>= 1) p += __shfl_down(p, off, 64);
        if (lane == 0) qv[r] = p + qb[r];
    }
    __syncthreads();
    float u0 = 0.f, u1 = 0.f;
    for (int o = 0; o < 512; o++) {
        float qc = qv[o];
        u0 = fmaf(kw[(size_t)o * 512 + tid], qc, u0);
        u1 = fmaf(kw[(size_t)o * 512 + tid + 256], qc, u1);
    }
    u_all[(size_t)cd * 512 + tid] = u0;
    u_all[(size_t)cd * 512 + tid + 256] = u1;
    float pk = qv[tid] * kb[tid] + qv[tid + 256] * kb[tid + 256];
    for (int off = 32; off; off >>= 1) pk += __shfl_down(pk, off, 64);
    __shared__ float pr[4];
    if (lane == 0) pr[w] = pk;
    __syncthreads();
    if (tid == 0) qkbg[cd] = pr[0] + pr[1] + pr[2] + pr[3];
}

// ---------------------------------------------------------------------------
// K7: maxex9[cd][bp][mc] = max over 64-pixel chunk of u.x5[bp,:,m].
// Single-barrier reduction.
// ---------------------------------------------------------------------------
__global__ __launch_bounds__(256)
void refine_max_kernel(const float* __restrict__ x5, const float* __restrict__ u_all,
                       float* __restrict__ maxex9)
{
    int bp = blockIdx.x, cg = blockIdx.y, mc = blockIdx.z;
    int tid = threadIdx.x, mi = tid & 63, cs = tid >> 6;
    int m0 = mc * 64;
    __shared__ float us[16 * 512];       // 32 KB
    __shared__ float red[16][4][64];     // 16 KB
    for (int e = tid; e < 16 * 512; e += 256) us[e] = u_all[(size_t)cg * 16 * 512 + e];
    __syncthreads();

    float acc[16];
#pragma unroll
    for (int j = 0; j < 16; j++) acc[j] = 0.f;
    const float* xb = x5 + (size_t)bp * CHW + m0 + mi;
    for (int cc = 0; cc < 128; cc++) {
        int c = cs * 128 + cc;
        float x = xb[(size_t)c * HWW];
#pragma unroll
        for (int j = 0; j < 16; j++)
            acc[j] = fmaf(us[j * 512 + c], x, acc[j]);
    }
#pragma unroll
    for (int j = 0; j < 16; j++) red[j][cs][mi] = acc[j];
    __syncthreads();
    if (tid < 64) {
#pragma unroll
        for (int j = 0; j < 16; j++) {
            float v = red[j][0][tid] + red[j][1][tid] + red[j][2][tid] + red[j][3][tid];
            for (int off = 32; off; off >>= 1) v = fmaxf(v, __shfl_xor(v, off, 64));
            if (tid == j) maxex9[((size_t)(cg * 16 + j) * BB + bp) * 9 + mc] = v;
        }
    }
}

// ---------------------------------------------------------------------------
// K8: exact argmax among candidates -> one-hot mask + chosen index
// ---------------------------------------------------------------------------
__global__ __launch_bounds__(576)
void mask_kernel(const float* __restrict__ maxex9, const float* __restrict__ qkbg,
                 const int* __restrict__ cand, float* __restrict__ maskout,
                 int* __restrict__ chosenidx)
{
    int bi = blockIdx.x, m = threadIdx.x;
    __shared__ float ve[4];
    __shared__ int chosen;
    if (m < 4) {
        int cd = bi * 4 + m;
        float sacc = 0.f;
#pragma unroll
        for (int t = 0; t < BB; t++) {
            const float* p = maxex9 + ((size_t)cd * BB + t) * 9;
            float mv = p[0];
#pragma unroll
            for (int z = 1; z < 9; z++) mv = fmaxf(mv, p[z]);
            sacc += mv;
        }
        ve[m] = sacc * (1.f / 16.f) + qkbg[cd];
    }
    __syncthreads();
    if (m == 0) {
        int best = 0; float bv = ve[0];
        for (int j = 1; j < 4; j++) if (ve[j] > bv) { bv = ve[j]; best = j; }
        chosen = cand[bi * 4 + best];
        chosenidx[bi] = chosen;
    }
    __syncthreads();
    maskout[bi * HWW + m] = (m == chosen) ? 1.f : 0.f;
}

// ---------------------------------------------------------------------------
// K9: inv[b,m] = 1/max(sqrt(sum_c x5^2), 1e-12)
// ---------------------------------------------------------------------------
__global__ __launch_bounds__(256)
void norm_kernel(const float* __restrict__ X5, float* __restrict__ invb)
{
    int b = blockIdx.y;
    int m0 = blockIdx.x * 64;
    int mi = threadIdx.x & 63, cs = threadIdx.x >> 6;
    float s = 0.f;
    for (int c = cs; c < CC; c += 4) {
        float x = X5[b * CHW + c * HWW + m0 + mi];
        s = fmaf(x, x, s);
    }
    __shared__ float red[4][64];
    red[cs][mi] = s;
    __syncthreads();
    if (cs == 0) {
        float t = red[0][mi] + red[1][mi] + red[2][mi] + red[3][mi];
        invb[b * HWW + m0 + mi] = 1.0f / fmaxf(sqrtf(t), 1e-12f);
    }
}

// ---------------------------------------------------------------------------
// K10: seeds via one-hot identity: seeds[s,c] = x5[s,c,m*] * inv[s,m*]
// ---------------------------------------------------------------------------
__global__ __launch_bounds__(512)
void seeds_direct_kernel(const float* __restrict__ X5, const float* __restrict__ invb,
                         const int* __restrict__ chosenidx, float* __restrict__ seeds)
{
    int s = blockIdx.x, c = threadIdx.x;
    int mstar = chosenidx[s];
    float w = invb[s * HWW + mstar];
    seeds[s * CC + c] = X5[(size_t)s * CHW + (size_t)c * HWW + mstar] * w;
}

// ---------------------------------------------------------------------------
// K11: corr[b,m] = inv[b,m]/16 * sum_s relu( sum_c x5[b,c,m]*seeds[s,c] )
// ---------------------------------------------------------------------------
__global__ __launch_bounds__(256)
void corr_kernel(const float* __restrict__ X5, const float* __restrict__ invb,
                 const float* __restrict__ seeds, float* __restrict__ corr)
{
    __shared__ float sd[16 * 512];
    __shared__ float xs[64][65];
    __shared__ float red[4][64];
    int b = blockIdx.y;
    int m0 = blockIdx.x * 64;
    int tid = threadIdx.x;
    int mi = tid & 63, sg = tid >> 6;

    for (int e = tid; e < 16 * 512; e += 256) sd[e] = seeds[e];

    float acc[4] = {0.f, 0.f, 0.f, 0.f};
    for (int c0 = 0; c0 < CC; c0 += 64) {
        __syncthreads();
        for (int e = tid; e < 4096; e += 256) {
            int mm = e & 63, kk = e >> 6;
            xs[kk][mm] = X5[b * CHW + (c0 + kk) * HWW + m0 + mm];
        }
        __syncthreads();
#pragma unroll
        for (int kk = 0; kk < 64; kk++) {
            float xv = xs[kk][mi];
#pragma unroll
            for (int t = 0; t < 4; t++)
                acc[t] = fmaf(xv, sd[(sg * 4 + t) * CC + c0 + kk], acc[t]);
        }
    }
    float r = 0.f;
#pragma unroll
    for (int t = 0; t < 4; t++) r += fmaxf(acc[t], 0.f);
    red[sg][mi] = r;
    __syncthreads();
    if (sg == 0) {
        float tot = red[0][mi] + red[1][mi] + red[2][mi] + red[3][mi];
        corr[b * HWW + m0 + mi] = invb[b * HWW + m0 + mi] * tot * (1.0f / 16.0f);
    }
}

// ---------------------------------------------------------------------------
// K12: per-image min/max normalize of corr -> cormap
// ---------------------------------------------------------------------------
__global__ __launch_bounds__(576)
void cormap_kernel(const float* __restrict__ corr, float* __restrict__ cormap)
{
    __shared__ float sv[576];
    __shared__ float smn[64], smx[64];
    __shared__ float s_mn, s_mx;
    int b = blockIdx.x;
    int m = threadIdx.x;
    float v = corr[b * HWW + m];
    sv[m] = v;
    __syncthreads();
    if (m < 64) {
        float mn = sv[m], mx = sv[m];
        for (int j = m + 64; j < 576; j += 64) { mn = fminf(mn, sv[j]); mx = fmaxf(mx, sv[j]); }
        smn[m] = mn; smx[m] = mx;
    }
    __syncthreads();
    if (m == 0) {
        float mn = smn[0], mx = smx[0];
        for (int j = 1; j < 64; j++) { mn = fminf(mn, smn[j]); mx = fmaxf(mx, smx[j]); }
        s_mn = mn; s_mx = mx;
    }
    __syncthreads();
    cormap[b * HWW + m] = (v - s_mn) / (s_mx - s_mn + 1e-12f);
}

// ---------------------------------------------------------------------------
// K13: proto1[c] = mean_{b,m} x5[b,c,m]*cormap[b,m]  (no int divides)
// ---------------------------------------------------------------------------
__global__ __launch_bounds__(256)
void proto_kernel(const float* __restrict__ X5, const float* __restrict__ cormap,
                  float* __restrict__ proto1)
{
    int c = blockIdx.x;
    int tid = threadIdx.x;
    float acc = 0.f;
    for (int b = 0; b < BB; b++) {
        const float* xp = X5 + (size_t)b * CHW + (size_t)c * HWW;
        const float* cp = cormap + b * HWW;
        for (int m = tid; m < HWW; m += 256)
            acc = fmaf(xp[m], cp[m], acc);
    }
    for (int off = 32; off > 0; off >>= 1) acc += __shfl_down(acc, off, 64);
    __shared__ float red[4];
    if ((tid & 63) == 0) red[tid >> 6] = acc;
    __syncthreads();
    if (tid == 0) proto1[c] = (red[0] + red[1] + red[2] + red[3]) * (1.0f / (float)NN);
}

// ---------------------------------------------------------------------------
// K14: out3 = x5*(proto1[c] + cormap[b,m])  (2-D grid, no divides)
// ---------------------------------------------------------------------------
__global__ __launch_bounds__(192)
void final_kernel(const float* __restrict__ X5, const float* __restrict__ proto1,
                  const float* __restrict__ cormap, float* __restrict__ out3)
{
    int c = blockIdx.x, b = blockIdx.y;
    size_t base = (size_t)b * CHW + (size_t)c * HWW;
    float pc = proto1[c];
    const float* cp = cormap + b * HWW;
#pragma unroll
    for (int k = 0; k < 3; k++) {
        int m = threadIdx.x + k * 192;
        out3[base + m] = X5[base + m] * (pc + cp[m]);
    }
}

// ---------------------------------------------------------------------------
extern "C" void kernel_launch(void* const* d_in, const int* in_sizes, int n_in,
                              void* d_out, int out_size, void* d_ws, size_t ws_size,
                              hipStream_t stream)
{
    const float* x  = (const float*)d_in[0];
    const float* cw = (const float*)d_in[1];
    const float* cb = (const float*)d_in[2];
    const float* qw = (const float*)d_in[3];
    const float* qb = (const float*)d_in[4];
    const float* kw = (const float*)d_in[5];
    const float* kb = (const float*)d_in[6];

    float* out     = (float*)d_out;
    float* x5o     = out;                        // output 0
    float* proto1  = out + TOT;                  // output 1
    float* out3    = out + TOT + 512;            // output 2
    float* maskout = out + TOT + 512 + TOT;      // output 3

    // out3 region overlays (all consumed before final_kernel writes out3):
    char* o3 = (char*)out3;
    __bf16* xlo    = (__bf16*)o3;
    __bf16* qfrag  = (__bf16*)o3;                // overwrites xlo after conv1
    __bf16* x5frag = (__bf16*)(o3 + FRAGB);

    // ws layout:
    char* ws = (char*)d_ws;
    __bf16* xhi   = (__bf16*)ws;                 // -> later kfrag (same slot)
    __bf16* kfrag = (__bf16*)ws;
    __bf16* cwhi  = (__bf16*)(ws + FRAGB);
    __bf16* cwlo  = (__bf16*)(ws + FRAGB + 524288);
    __bf16* qwf   = (__bf16*)(ws + FRAGB + 2 * 524288);
    __bf16* kwf   = (__bf16*)(ws + FRAGB + 3 * 524288);
    char* p = ws + FRAGB + 4 * 524288;
    float* maxv3  = (float*)p;   p += (size_t)NN * BB * 3 * 4;
    int*   cand   = (int*)p;     p += 256;
    int*   chosenidx = (int*)p;  p += 256;
    float* u_all  = (float*)p;   p += 64 * 512 * 4;
    float* qkbg   = (float*)p;   p += 256;
    float* maxex9 = (float*)p;   p += 64 * BB * 9 * 4;
    float* invb   = (float*)p;   p += NN * 4;
    float* corr   = (float*)p;   p += NN * 4;
    float* cmap   = (float*)p;   p += NN * 4;
    float* seeds  = (float*)p;   p += BB * CC * 4;

    prep_x_kernel<<<NN * 64 / 256, 256, 0, stream>>>(x, xhi, xlo);
    prep_w_kernel<<<dim3(128, 3), 256, 0, stream>>>(cw, qw, kw, cwhi, cwlo, qwf, kwf);

    conv1_mfma_kernel<<<dim3(NN / 128, 4), 256, 0, stream>>>(x, cwhi, cwlo, xhi, xlo, cb, x5o, x5frag);
    convqk_mfma_kernel<<<dim3(NN / 128, 4, 2), 256, 0, stream>>>(qwf, kwf, qb, kb, x5frag, qfrag, kfrag);

    scores_mfma_kernel<<<3456, 256, 0, stream>>>(qfrag, kfrag, maxv3);

    topk_kernel<<<BB, HWW, 0, stream>>>(maxv3, cand);
    refine_qu_kernel<<<64, 256, 0, stream>>>(x5o, qw, qb, kw, kb, cand, u_all, qkbg);
    refine_max_kernel<<<dim3(BB, 4, 9), 256, 0, stream>>>(x5o, u_all, maxex9);
    mask_kernel<<<BB, HWW, 0, stream>>>(maxex9, qkbg, cand, maskout, chosenidx);

    norm_kernel<<<dim3(9, BB), 256, 0, stream>>>(x5o, invb);
    seeds_direct_kernel<<<BB, 512, 0, stream>>>(x5o, invb, chosenidx, seeds);
    corr_kernel<<<dim3(9, BB), 256, 0, stream>>>(x5o, invb, seeds, corr);
    cormap_kernel<<<BB, HWW, 0, stream>>>(corr, cmap);
    proto_kernel<<<CC, 256, 0, stream>>>(x5o, cmap, proto1);
    final_kernel<<<dim3(CC, BB), 192, 0, stream>>>(x5o, proto1, cmap, out3);
}

// Round 8
// 371.202 us; speedup vs baseline: 1.1972x; 1.1972x over previous
//
#include <hip/hip_runtime.h>
#include <math.h>

#define BB   16
#define CC   512
#define HWW  576
#define NN   9216            // B*HW
#define CHW  (CC*HWW)        // 294912
#define TOT  (BB*CHW)        // 4718592
#define SCALE 0.044194173824159216f  // 1/sqrt(512)
#define FRAGB 9437184        // NN*CC bf16 bytes

typedef __attribute__((ext_vector_type(8))) __bf16 bf16x8;
typedef __attribute__((ext_vector_type(4))) float f32x4;

#define AS1 __attribute__((address_space(1)))
#define AS3 __attribute__((address_space(3)))

// async 16B global->LDS: lds dest = wave-uniform base + lane*16
static __device__ __forceinline__ void gload_lds16(const void* g, void* l)
{
    __builtin_amdgcn_global_load_lds((AS1 const void*)g, (AS3 void*)l, 16, 0, 0);
}

// ---------------------------------------------------------------------------
// Fragment-linear bf16 layout (MFMA A/B operand order), 64x64 (dim,k) blocks:
//   slot(elem) = (s*4+g4)*512 + L*8 + j,  L = (q8<<4)|Lm
//   dim64 = g4*16 + Lm,   k64 = s*32 + q8*8 + j
// X/x5/q/k ("B-side", dim=pixel, k=channel): block index [Cb*144 + T]
// W ("A-side", dim=out-chan, k=in-chan):     block index [Cb*8  + To]
// Frag read for mfma_16x16x32_bf16: contiguous 16 B at lane*16.
// ---------------------------------------------------------------------------

// P1: x -> hi/lo bf16 fragment layout
__global__ __launch_bounds__(256)
void prep_x_kernel(const float* __restrict__ X, __bf16* __restrict__ Xhi,
                   __bf16* __restrict__ Xlo)
{
    int g = blockIdx.x * 256 + threadIdx.x;   // NN*64 threads
    int n = g % NN;
    int co = g / NN;                          // channel octet 0..63
    int c0 = co * 8;
    int bimg = n / HWW, mm = n % HWW;
    const float* src = X + (size_t)bimg * CHW + mm;
    union { __bf16 h[8]; float4 f4; } uh, ul;
#pragma unroll
    for (int j = 0; j < 8; j++) {
        float v = src[(size_t)(c0 + j) * HWW];
        __bf16 h = (__bf16)v;
        uh.h[j] = h;
        ul.h[j] = (__bf16)(v - (float)h);
    }
    int Cb = c0 >> 6, s = (c0 >> 5) & 1, q8 = (c0 >> 3) & 3;
    int T = n >> 6, g4 = (n >> 4) & 3, Lm = n & 15;
    size_t off = (size_t)(Cb * 144 + T) * 4096 + (s * 4 + g4) * 512 + (size_t)((q8 << 4) | Lm) * 8;
    *(float4*)&Xhi[off] = uh.f4;
    *(float4*)&Xlo[off] = ul.f4;
}

// P2: weights -> fragment layout. y=0: cw (hi+lo), y=1: qw, y=2: kw
__global__ __launch_bounds__(256)
void prep_w_kernel(const float* __restrict__ cw, const float* __restrict__ qw,
                   const float* __restrict__ kw, __bf16* __restrict__ cwhi,
                   __bf16* __restrict__ cwlo, __bf16* __restrict__ qwf,
                   __bf16* __restrict__ kwf)
{
    int y = blockIdx.y;
    const float* W = (y == 0) ? cw : (y == 1) ? qw : kw;
    __bf16* dh = (y == 0) ? cwhi : (y == 1) ? qwf : kwf;
    int g = blockIdx.x * 256 + threadIdx.x;   // 512*64 threads
    int o = g >> 6;
    int c0 = (g & 63) * 8;
    union { __bf16 h[8]; float4 f4; } uh, ul;
#pragma unroll
    for (int j = 0; j < 8; j++) {
        float v = W[(size_t)o * CC + c0 + j];
        __bf16 h = (__bf16)v;
        uh.h[j] = h;
        ul.h[j] = (__bf16)(v - (float)h);
    }
    int Cb = c0 >> 6, s = (c0 >> 5) & 1, q8 = (c0 >> 3) & 3;
    int To = o >> 6, g4 = (o >> 4) & 3, Lm = o & 15;
    size_t off = (size_t)(Cb * 8 + To) * 4096 + (s * 4 + g4) * 512 + (size_t)((q8 << 4) | Lm) * 8;
    *(float4*)&dh[off] = uh.f4;
    if (y == 0) *(float4*)&cwlo[off] = ul.f4;
}

// ---------------------------------------------------------------------------
// K1: x5 conv via hi/lo bf16 MFMA (fp32-class accuracy) + residual + bias.
// Round-5 structure: async LDS staging for A(hi/lo) and B(hi/lo).
// ---------------------------------------------------------------------------
__global__ __launch_bounds__(256)
void conv1_mfma_kernel(const float* __restrict__ X, const __bf16* __restrict__ Whi,
                       const __bf16* __restrict__ Wlo, const __bf16* __restrict__ Xhi,
                       const __bf16* __restrict__ Xlo, const float* __restrict__ bias,
                       float* __restrict__ Y, __bf16* __restrict__ Yfrag)
{
    __shared__ __bf16 lAh[8192], lAl[8192], lBh[8192], lBl[8192];
    int tid = threadIdx.x, lane = tid & 63, wv = tid >> 6;
    int wo = wv >> 1, wm = wv & 1;
    int m0 = blockIdx.x * 128;
    int o0 = blockIdx.y * 128;
    int oT0 = blockIdx.y * 2, mT0 = blockIdx.x * 2;

    f32x4 acc[4][4];
#pragma unroll
    for (int i = 0; i < 4; i++)
#pragma unroll
        for (int j = 0; j < 4; j++) acc[i][j] = (f32x4){0.f, 0.f, 0.f, 0.f};

    for (int Cb = 0; Cb < 8; Cb++) {
        const float4* gAh = (const float4*)(Whi + (size_t)(Cb * 8 + oT0) * 4096);
        const float4* gAl = (const float4*)(Wlo + (size_t)(Cb * 8 + oT0) * 4096);
        const float4* gBh = (const float4*)(Xhi + (size_t)(Cb * 144 + mT0) * 4096);
        const float4* gBl = (const float4*)(Xlo + (size_t)(Cb * 144 + mT0) * 4096);
#pragma unroll
        for (int i = 0; i < 4; i++) {
            int eb = wv * 256 + i * 64;
            gload_lds16(gAh + eb + lane, (float4*)lAh + eb);
            gload_lds16(gAl + eb + lane, (float4*)lAl + eb);
            gload_lds16(gBh + eb + lane, (float4*)lBh + eb);
            gload_lds16(gBl + eb + lane, (float4*)lBl + eb);
        }
        __syncthreads();
#pragma unroll
        for (int s = 0; s < 2; s++) {
            bf16x8 ah[4], al[4], bh[4], bl[4];
#pragma unroll
            for (int ga = 0; ga < 4; ga++) {
                ah[ga] = *(const bf16x8*)&lAh[wo * 4096 + (s * 4 + ga) * 512 + lane * 8];
                al[ga] = *(const bf16x8*)&lAl[wo * 4096 + (s * 4 + ga) * 512 + lane * 8];
            }
#pragma unroll
            for (int gb = 0; gb < 4; gb++) {
                bh[gb] = *(const bf16x8*)&lBh[wm * 4096 + (s * 4 + gb) * 512 + lane * 8];
                bl[gb] = *(const bf16x8*)&lBl[wm * 4096 + (s * 4 + gb) * 512 + lane * 8];
            }
#pragma unroll
            for (int ga = 0; ga < 4; ga++)
#pragma unroll
                for (int gb = 0; gb < 4; gb++) {
                    acc[ga][gb] = __builtin_amdgcn_mfma_f32_16x16x32_bf16(ah[ga], bh[gb], acc[ga][gb], 0, 0, 0);
                    acc[ga][gb] = __builtin_amdgcn_mfma_f32_16x16x32_bf16(ah[ga], bl[gb], acc[ga][gb], 0, 0, 0);
                    acc[ga][gb] = __builtin_amdgcn_mfma_f32_16x16x32_bf16(al[ga], bh[gb], acc[ga][gb], 0, 0, 0);
                }
        }
        __syncthreads();
    }

    int quad = lane >> 4, col = lane & 15;
#pragma unroll
    for (int ga = 0; ga < 4; ga++) {
        int ob = o0 + wo * 64 + ga * 16 + quad * 4;
        float bs[4];
#pragma unroll
        for (int r = 0; r < 4; r++) bs[r] = bias[ob + r];
        int Cb2 = ob >> 6, s2 = (ob >> 5) & 1, q8 = (ob >> 3) & 3, j0 = ob & 7;
#pragma unroll
        for (int gb = 0; gb < 4; gb++) {
            int n = m0 + wm * 64 + gb * 16 + col;
            int T = n >> 6, g4 = (n >> 4) & 3, Lm = n & 15;
            int bimg = n / HWW, mm = n % HWW;
            size_t xb = (size_t)bimg * CHW + mm;
            union { __bf16 h[4]; float2 f2; } u;
#pragma unroll
            for (int r = 0; r < 4; r++) {
                float v = acc[ga][gb][r] + bs[r] + X[xb + (size_t)(ob + r) * HWW];
                Y[xb + (size_t)(ob + r) * HWW] = v;
                u.h[r] = (__bf16)v;
            }
            *(float2*)&Yfrag[(size_t)(Cb2 * 144 + T) * 4096 + (s2 * 4 + g4) * 512 + (size_t)((q8 << 4) | Lm) * 8 + j0] = u.f2;
        }
    }
}

// ---------------------------------------------------------------------------
// K2: q & k convs via plain bf16 MFMA, round-5 structure (LDS A + B).
// ---------------------------------------------------------------------------
__global__ __launch_bounds__(256)
void convqk_mfma_kernel(const __bf16* __restrict__ qwf, const __bf16* __restrict__ kwf,
                        const float* __restrict__ qb, const float* __restrict__ kb,
                        const __bf16* __restrict__ Xf, __bf16* __restrict__ Oq,
                        __bf16* __restrict__ Ok)
{
    const __bf16* Wf = blockIdx.z ? kwf : qwf;
    const float* bias = blockIdx.z ? kb : qb;
    __bf16* Of = blockIdx.z ? Ok : Oq;

    __shared__ __bf16 lA[8192], lB[8192];
    int tid = threadIdx.x, lane = tid & 63, wv = tid >> 6;
    int wo = wv >> 1, wm = wv & 1;
    int m0 = blockIdx.x * 128;
    int o0 = blockIdx.y * 128;
    int oT0 = blockIdx.y * 2, mT0 = blockIdx.x * 2;

    f32x4 acc[4][4];
#pragma unroll
    for (int i = 0; i < 4; i++)
#pragma unroll
        for (int j = 0; j < 4; j++) acc[i][j] = (f32x4){0.f, 0.f, 0.f, 0.f};

    for (int Cb = 0; Cb < 8; Cb++) {
        const float4* gA = (const float4*)(Wf + (size_t)(Cb * 8 + oT0) * 4096);
        const float4* gB = (const float4*)(Xf + (size_t)(Cb * 144 + mT0) * 4096);
#pragma unroll
        for (int i = 0; i < 4; i++) {
            int eb = wv * 256 + i * 64;
            gload_lds16(gA + eb + lane, (float4*)lA + eb);
            gload_lds16(gB + eb + lane, (float4*)lB + eb);
        }
        __syncthreads();
#pragma unroll
        for (int s = 0; s < 2; s++) {
            bf16x8 af[4], bf[4];
#pragma unroll
            for (int ga = 0; ga < 4; ga++)
                af[ga] = *(const bf16x8*)&lA[wo * 4096 + (s * 4 + ga) * 512 + lane * 8];
#pragma unroll
            for (int gb = 0; gb < 4; gb++)
                bf[gb] = *(const bf16x8*)&lB[wm * 4096 + (s * 4 + gb) * 512 + lane * 8];
#pragma unroll
            for (int ga = 0; ga < 4; ga++)
#pragma unroll
                for (int gb = 0; gb < 4; gb++)
                    acc[ga][gb] = __builtin_amdgcn_mfma_f32_16x16x32_bf16(af[ga], bf[gb], acc[ga][gb], 0, 0, 0);
        }
        __syncthreads();
    }

    int quad = lane >> 4, col = lane & 15;
#pragma unroll
    for (int ga = 0; ga < 4; ga++) {
        int ob = o0 + wo * 64 + ga * 16 + quad * 4;
        float bs[4];
#pragma unroll
        for (int r = 0; r < 4; r++) bs[r] = bias[ob + r];
        int Cb2 = ob >> 6, s2 = (ob >> 5) & 1, q8 = (ob >> 3) & 3, j0 = ob & 7;
#pragma unroll
        for (int gb = 0; gb < 4; gb++) {
            int n = m0 + wm * 64 + gb * 16 + col;
            int T = n >> 6, g4 = (n >> 4) & 3, Lm = n & 15;
            union { __bf16 h[4]; float2 f2; } u;
#pragma unroll
            for (int r = 0; r < 4; r++) u.h[r] = (__bf16)(acc[ga][gb][r] + bs[r]);
            *(float2*)&Of[(size_t)(Cb2 * 144 + T) * 4096 + (s2 * 4 + g4) * 512 + (size_t)((q8 << 4) | Lm) * 8 + j0] = u.f2;
        }
    }
}

// ---------------------------------------------------------------------------
// K4: scores GEMM + max. Round-5 exact structure (measured 105.9 us):
// block 128q x 192k, wave 64x96, async staging, 40 KB LDS, 2-D grid.
// ---------------------------------------------------------------------------
__global__ __launch_bounds__(256)
void scores_mfma_kernel(const __bf16* __restrict__ Qf, const __bf16* __restrict__ Kf,
                        float* __restrict__ maxv3)
{
    __shared__ __bf16 ldsQ[8192];    // 16 KB (redbuf aliases)
    __shared__ __bf16 ldsK[12288];   // 24 KB

    int tid = threadIdx.x, lane = tid & 63, wv = tid >> 6;
    int wq = wv >> 1, wk = wv & 1;
    int bx = blockIdx.x;
    int n0 = bx * 128;
    int b = blockIdx.y / 3, mt = blockIdx.y % 3;

    f32x4 acc[4][6];
#pragma unroll
    for (int ga = 0; ga < 4; ga++)
#pragma unroll
        for (int t = 0; t < 6; t++) acc[ga][t] = (f32x4){0.f, 0.f, 0.f, 0.f};

    const __bf16* qbase = Qf + (size_t)(bx * 2) * 4096;
    const __bf16* kbase = Kf + (size_t)(b * 9 + mt * 3) * 4096;

    for (int C = 0; C < 8; C++) {
        const float4* gq = (const float4*)(qbase + (size_t)C * 144 * 4096);
        const float4* gk = (const float4*)(kbase + (size_t)C * 144 * 4096);
#pragma unroll
        for (int i = 0; i < 4; i++) {
            int eb = wv * 256 + i * 64;
            gload_lds16(gq + eb + lane, (float4*)ldsQ + eb);
        }
#pragma unroll
        for (int i = 0; i < 6; i++) {
            int eb = wv * 384 + i * 64;
            gload_lds16(gk + eb + lane, (float4*)ldsK + eb);
        }
        __syncthreads();
#pragma unroll
        for (int s = 0; s < 2; s++) {
            bf16x8 af[4];
#pragma unroll
            for (int ga = 0; ga < 4; ga++)
                af[ga] = *(const bf16x8*)&ldsQ[wq * 4096 + (s * 4 + ga) * 512 + lane * 8];
#pragma unroll
            for (int t = 0; t < 6; t++) {
                int mkl = wk * 96 + t * 16;
                bf16x8 bfr = *(const bf16x8*)&ldsK[(mkl >> 6) * 4096 + (s * 4 + ((mkl >> 4) & 3)) * 512 + lane * 8];
#pragma unroll
                for (int ga = 0; ga < 4; ga++)
                    acc[ga][t] = __builtin_amdgcn_mfma_f32_16x16x32_bf16(af[ga], bfr, acc[ga][t], 0, 0, 0);
            }
        }
        __syncthreads();
    }

    float mg[4][4];
#pragma unroll
    for (int ga = 0; ga < 4; ga++)
#pragma unroll
        for (int r = 0; r < 4; r++) {
            float v = acc[ga][0][r];
#pragma unroll
            for (int t = 1; t < 6; t++) v = fmaxf(v, acc[ga][t][r]);
            mg[ga][r] = v;
        }
#pragma unroll
    for (int off = 1; off < 16; off <<= 1)
#pragma unroll
        for (int ga = 0; ga < 4; ga++)
#pragma unroll
            for (int r = 0; r < 4; r++)
                mg[ga][r] = fmaxf(mg[ga][r], __shfl_xor(mg[ga][r], off, 64));

    float (*redbuf)[2] = (float (*)[2])ldsQ;
    if ((lane & 15) == 0) {
        int quad = lane >> 4;
#pragma unroll
        for (int ga = 0; ga < 4; ga++)
#pragma unroll
            for (int r = 0; r < 4; r++)
                redbuf[wq * 64 + ga * 16 + quad * 4 + r][wk] = mg[ga][r];
    }
    __syncthreads();
    if (tid < 128) {
        float rv = fmaxf(redbuf[tid][0], redbuf[tid][1]) * SCALE;
        maxv3[((size_t)(n0 + tid) * BB + b) * 3 + mt] = rv;
    }
}

// ---------------------------------------------------------------------------
// K5: approx v, top-4 candidates per image.
// ---------------------------------------------------------------------------
__global__ __launch_bounds__(576)
void topk_kernel(const float* __restrict__ maxv3, int* __restrict__ cand)
{
    __shared__ float sv[576];
    __shared__ float rv_[64];
    __shared__ int ri_[64];
    int bi = blockIdx.x, m = threadIdx.x;
    int n = bi * HWW + m;
    float v = 0.f;
#pragma unroll
    for (int t = 0; t < BB; t++) {
        const float* p = maxv3 + ((size_t)n * BB + t) * 3;
        v += fmaxf(fmaxf(p[0], p[1]), p[2]);
    }
    sv[m] = v;
    __syncthreads();
    for (int r = 0; r < 4; r++) {
        if (m < 64) {
            float bv = sv[m]; int bidx = m;
            for (int j = m + 64; j < 576; j += 64)
                if (sv[j] > bv) { bv = sv[j]; bidx = j; }
            rv_[m] = bv; ri_[m] = bidx;
        }
        __syncthreads();
        if (m == 0) {
            float bv = rv_[0]; int bidx = ri_[0];
            for (int j = 1; j < 64; j++)
                if (rv_[j] > bv) { bv = rv_[j]; bidx = ri_[j]; }
            cand[bi * 4 + r] = bidx;
            sv[bidx] = -3.4e38f;
        }
        __syncthreads();
    }
}

// ---------------------------------------------------------------------------
// K6a: q = Qw * xcol + qb for each candidate (round-5 split version).
// ---------------------------------------------------------------------------
__global__ __launch_bounds__(256)
void refine_q_kernel(const float* __restrict__ x5, const float* __restrict__ qw,
                     const float* __restrict__ qb, const int* __restrict__ cand,
                     float* __restrict__ q_all)
{
    int og = blockIdx.x, cd = blockIdx.y;
    int bi = cd >> 2;
    int mstar = cand[cd];
    int tid = threadIdx.x, w = tid >> 6, lane = tid & 63;
    __shared__ float xcol[512];
    __shared__ float qrows[64];
    xcol[tid]       = x5[(size_t)bi * CHW + tid * HWW + mstar];
    xcol[tid + 256] = x5[(size_t)bi * CHW + (tid + 256) * HWW + mstar];
    __syncthreads();
#pragma unroll
    for (int i = 0; i < 16; i++) {
        int r = og * 64 + w * 16 + i;
        float p = 0.f;
#pragma unroll
        for (int it = 0; it < 8; it++) {
            int c = lane + it * 64;
            p = fmaf(qw[(size_t)r * 512 + c], xcol[c], p);
        }
        for (int off = 32; off; off >>= 1) p += __shfl_down(p, off, 64);
        if (lane == 0) qrows[w * 16 + i] = p;
    }
    __syncthreads();
    if (tid < 64) q_all[(size_t)cd * 512 + og * 64 + tid] = qrows[tid] + qb[og * 64 + tid];
}

// ---------------------------------------------------------------------------
// K6b: u[t] = sum_o Kw[o,t]*q[o] (coalesced kw), + qkb (round-5 split).
// ---------------------------------------------------------------------------
__global__ __launch_bounds__(256)
void refine_u2_kernel(const float* __restrict__ kw, const float* __restrict__ kb,
                      const float* __restrict__ q_all, float* __restrict__ u_all,
                      float* __restrict__ qkbg)
{
    int tg = blockIdx.x, cd = blockIdx.y;
    int tid = threadIdx.x;
    __shared__ float qs[512];
    qs[tid]       = q_all[(size_t)cd * 512 + tid];
    qs[tid + 256] = q_all[(size_t)cd * 512 + tid + 256];
    __syncthreads();
    int t = tg * 256 + tid;
    float u = 0.f;
    for (int o = 0; o < 512; o++)
        u = fmaf(kw[(size_t)o * 512 + t], qs[o], u);
    u_all[(size_t)cd * 512 + t] = u;
    if (tg == 0) {
        float pk = qs[tid] * kb[tid] + qs[tid + 256] * kb[tid + 256];
        for (int off = 32; off; off >>= 1) pk += __shfl_down(pk, off, 64);
        __shared__ float pr[4];
        if ((tid & 63) == 0) pr[tid >> 6] = pk;
        __syncthreads();
        if (tid == 0) qkbg[cd] = pr[0] + pr[1] + pr[2] + pr[3];
    }
}

// ---------------------------------------------------------------------------
// K7: maxex9[cd][bp][mc] = max over 64-pixel chunk of u.x5[bp,:,m].
// Single-barrier reduction (round-7 improvement, kept).
// ---------------------------------------------------------------------------
__global__ __launch_bounds__(256)
void refine_max_kernel(const float* __restrict__ x5, const float* __restrict__ u_all,
                       float* __restrict__ maxex9)
{
    int bp = blockIdx.x, cg = blockIdx.y, mc = blockIdx.z;
    int tid = threadIdx.x, mi = tid & 63, cs = tid >> 6;
    int m0 = mc * 64;
    __shared__ float us[16 * 512];       // 32 KB
    __shared__ float red[16][4][64];     // 16 KB
    for (int e = tid; e < 16 * 512; e += 256) us[e] = u_all[(size_t)cg * 16 * 512 + e];
    __syncthreads();

    float acc[16];
#pragma unroll
    for (int j = 0; j < 16; j++) acc[j] = 0.f;
    const float* xb = x5 + (size_t)bp * CHW + m0 + mi;
    for (int cc = 0; cc < 128; cc++) {
        int c = cs * 128 + cc;
        float x = xb[(size_t)c * HWW];
#pragma unroll
        for (int j = 0; j < 16; j++)
            acc[j] = fmaf(us[j * 512 + c], x, acc[j]);
    }
#pragma unroll
    for (int j = 0; j < 16; j++) red[j][cs][mi] = acc[j];
    __syncthreads();
    if (tid < 64) {
#pragma unroll
        for (int j = 0; j < 16; j++) {
            float v = red[j][0][tid] + red[j][1][tid] + red[j][2][tid] + red[j][3][tid];
            for (int off = 32; off; off >>= 1) v = fmaxf(v, __shfl_xor(v, off, 64));
            if (tid == j) maxex9[((size_t)(cg * 16 + j) * BB + bp) * 9 + mc] = v;
        }
    }
}

// ---------------------------------------------------------------------------
// K8: exact argmax among candidates -> one-hot mask + chosen index
// ---------------------------------------------------------------------------
__global__ __launch_bounds__(576)
void mask_kernel(const float* __restrict__ maxex9, const float* __restrict__ qkbg,
                 const int* __restrict__ cand, float* __restrict__ maskout,
                 int* __restrict__ chosenidx)
{
    int bi = blockIdx.x, m = threadIdx.x;
    __shared__ float ve[4];
    __shared__ int chosen;
    if (m < 4) {
        int cd = bi * 4 + m;
        float sacc = 0.f;
#pragma unroll
        for (int t = 0; t < BB; t++) {
            const float* p = maxex9 + ((size_t)cd * BB + t) * 9;
            float mv = p[0];
#pragma unroll
            for (int z = 1; z < 9; z++) mv = fmaxf(mv, p[z]);
            sacc += mv;
        }
        ve[m] = sacc * (1.f / 16.f) + qkbg[cd];
    }
    __syncthreads();
    if (m == 0) {
        int best = 0; float bv = ve[0];
        for (int j = 1; j < 4; j++) if (ve[j] > bv) { bv = ve[j]; best = j; }
        chosen = cand[bi * 4 + best];
        chosenidx[bi] = chosen;
    }
    __syncthreads();
    maskout[bi * HWW + m] = (m == chosen) ? 1.f : 0.f;
}

// ---------------------------------------------------------------------------
// K9: inv[b,m] = 1/max(sqrt(sum_c x5^2), 1e-12)
// ---------------------------------------------------------------------------
__global__ __launch_bounds__(256)
void norm_kernel(const float* __restrict__ X5, float* __restrict__ invb)
{
    int b = blockIdx.y;
    int m0 = blockIdx.x * 64;
    int mi = threadIdx.x & 63, cs = threadIdx.x >> 6;
    float s = 0.f;
    for (int c = cs; c < CC; c += 4) {
        float x = X5[b * CHW + c * HWW + m0 + mi];
        s = fmaf(x, x, s);
    }
    __shared__ float red[4][64];
    red[cs][mi] = s;
    __syncthreads();
    if (cs == 0) {
        float t = red[0][mi] + red[1][mi] + red[2][mi] + red[3][mi];
        invb[b * HWW + m0 + mi] = 1.0f / fmaxf(sqrtf(t), 1e-12f);
    }
}

// ---------------------------------------------------------------------------
// K10: seeds via one-hot identity: seeds[s,c] = x5[s,c,m*] * inv[s,m*]
// ---------------------------------------------------------------------------
__global__ __launch_bounds__(512)
void seeds_direct_kernel(const float* __restrict__ X5, const float* __restrict__ invb,
                         const int* __restrict__ chosenidx, float* __restrict__ seeds)
{
    int s = blockIdx.x, c = threadIdx.x;
    int mstar = chosenidx[s];
    float w = invb[s * HWW + mstar];
    seeds[s * CC + c] = X5[(size_t)s * CHW + (size_t)c * HWW + mstar] * w;
}

// ---------------------------------------------------------------------------
// K11: corr[b,m] = inv[b,m]/16 * sum_s relu( sum_c x5[b,c,m]*seeds[s,c] )
// ---------------------------------------------------------------------------
__global__ __launch_bounds__(256)
void corr_kernel(const float* __restrict__ X5, const float* __restrict__ invb,
                 const float* __restrict__ seeds, float* __restrict__ corr)
{
    __shared__ float sd[16 * 512];
    __shared__ float xs[64][65];
    __shared__ float red[4][64];
    int b = blockIdx.y;
    int m0 = blockIdx.x * 64;
    int tid = threadIdx.x;
    int mi = tid & 63, sg = tid >> 6;

    for (int e = tid; e < 16 * 512; e += 256) sd[e] = seeds[e];

    float acc[4] = {0.f, 0.f, 0.f, 0.f};
    for (int c0 = 0; c0 < CC; c0 += 64) {
        __syncthreads();
        for (int e = tid; e < 4096; e += 256) {
            int mm = e & 63, kk = e >> 6;
            xs[kk][mm] = X5[b * CHW + (c0 + kk) * HWW + m0 + mm];
        }
        __syncthreads();
#pragma unroll
        for (int kk = 0; kk < 64; kk++) {
            float xv = xs[kk][mi];
#pragma unroll
            for (int t = 0; t < 4; t++)
                acc[t] = fmaf(xv, sd[(sg * 4 + t) * CC + c0 + kk], acc[t]);
        }
    }
    float r = 0.f;
#pragma unroll
    for (int t = 0; t < 4; t++) r += fmaxf(acc[t], 0.f);
    red[sg][mi] = r;
    __syncthreads();
    if (sg == 0) {
        float tot = red[0][mi] + red[1][mi] + red[2][mi] + red[3][mi];
        corr[b * HWW + m0 + mi] = invb[b * HWW + m0 + mi] * tot * (1.0f / 16.0f);
    }
}

// ---------------------------------------------------------------------------
// K12: per-image min/max normalize of corr -> cormap
// ---------------------------------------------------------------------------
__global__ __launch_bounds__(576)
void cormap_kernel(const float* __restrict__ corr, float* __restrict__ cormap)
{
    __shared__ float sv[576];
    __shared__ float smn[64], smx[64];
    __shared__ float s_mn, s_mx;
    int b = blockIdx.x;
    int m = threadIdx.x;
    float v = corr[b * HWW + m];
    sv[m] = v;
    __syncthreads();
    if (m < 64) {
        float mn = sv[m], mx = sv[m];
        for (int j = m + 64; j < 576; j += 64) { mn = fminf(mn, sv[j]); mx = fmaxf(mx, sv[j]); }
        smn[m] = mn; smx[m] = mx;
    }
    __syncthreads();
    if (m == 0) {
        float mn = smn[0], mx = smx[0];
        for (int j = 1; j < 64; j++) { mn = fminf(mn, smn[j]); mx = fmaxf(mx, smx[j]); }
        s_mn = mn; s_mx = mx;
    }
    __syncthreads();
    cormap[b * HWW + m] = (v - s_mn) / (s_mx - s_mn + 1e-12f);
}

// ---------------------------------------------------------------------------
// K13: proto1[c] = mean_{b,m} x5[b,c,m]*cormap[b,m]  (no int divides)
// ---------------------------------------------------------------------------
__global__ __launch_bounds__(256)
void proto_kernel(const float* __restrict__ X5, const float* __restrict__ cormap,
                  float* __restrict__ proto1)
{
    int c = blockIdx.x;
    int tid = threadIdx.x;
    float acc = 0.f;
    for (int b = 0; b < BB; b++) {
        const float* xp = X5 + (size_t)b * CHW + (size_t)c * HWW;
        const float* cp = cormap + b * HWW;
        for (int m = tid; m < HWW; m += 256)
            acc = fmaf(xp[m], cp[m], acc);
    }
    for (int off = 32; off > 0; off >>= 1) acc += __shfl_down(acc, off, 64);
    __shared__ float red[4];
    if ((tid & 63) == 0) red[tid >> 6] = acc;
    __syncthreads();
    if (tid == 0) proto1[c] = (red[0] + red[1] + red[2] + red[3]) * (1.0f / (float)NN);
}

// ---------------------------------------------------------------------------
// K14: out3 = x5*(proto1[c] + cormap[b,m])  (2-D grid, no divides)
// ---------------------------------------------------------------------------
__global__ __launch_bounds__(192)
void final_kernel(const float* __restrict__ X5, const float* __restrict__ proto1,
                  const float* __restrict__ cormap, float* __restrict__ out3)
{
    int c = blockIdx.x, b = blockIdx.y;
    size_t base = (size_t)b * CHW + (size_t)c * HWW;
    float pc = proto1[c];
    const float* cp = cormap + b * HWW;
#pragma unroll
    for (int k = 0; k < 3; k++) {
        int m = threadIdx.x + k * 192;
        out3[base + m] = X5[base + m] * (pc + cp[m]);
    }
}

// ---------------------------------------------------------------------------
extern "C" void kernel_launch(void* const* d_in, const int* in_sizes, int n_in,
                              void* d_out, int out_size, void* d_ws, size_t ws_size,
                              hipStream_t stream)
{
    const float* x  = (const float*)d_in[0];
    const float* cw = (const float*)d_in[1];
    const float* cb = (const float*)d_in[2];
    const float* qw = (const float*)d_in[3];
    const float* qb = (const float*)d_in[4];
    const float* kw = (const float*)d_in[5];
    const float* kb = (const float*)d_in[6];

    float* out     = (float*)d_out;
    float* x5o     = out;                        // output 0
    float* proto1  = out + TOT;                  // output 1
    float* out3    = out + TOT + 512;            // output 2
    float* maskout = out + TOT + 512 + TOT;      // output 3

    // out3 region overlays (all consumed before final_kernel writes out3):
    char* o3 = (char*)out3;
    __bf16* xlo    = (__bf16*)o3;
    __bf16* qfrag  = (__bf16*)o3;                // overwrites xlo after conv1
    __bf16* x5frag = (__bf16*)(o3 + FRAGB);

    // ws layout:
    char* ws = (char*)d_ws;
    __bf16* xhi   = (__bf16*)ws;                 // -> later kfrag (same slot)
    __bf16* kfrag = (__bf16*)ws;
    __bf16* cwhi  = (__bf16*)(ws + FRAGB);
    __bf16* cwlo  = (__bf16*)(ws + FRAGB + 524288);
    __bf16* qwf   = (__bf16*)(ws + FRAGB + 2 * 524288);
    __bf16* kwf   = (__bf16*)(ws + FRAGB + 3 * 524288);
    char* p = ws + FRAGB + 4 * 524288;
    float* maxv3  = (float*)p;   p += (size_t)NN * BB * 3 * 4;
    int*   cand   = (int*)p;     p += 256;
    int*   chosenidx = (int*)p;  p += 256;
    float* q_all  = (float*)p;   p += 64 * 512 * 4;
    float* u_all  = (float*)p;   p += 64 * 512 * 4;
    float* qkbg   = (float*)p;   p += 256;
    float* maxex9 = (float*)p;   p += 64 * BB * 9 * 4;
    float* invb   = (float*)p;   p += NN * 4;
    float* corr   = (float*)p;   p += NN * 4;
    float* cmap   = (float*)p;   p += NN * 4;
    float* seeds  = (float*)p;   p += BB * CC * 4;

    prep_x_kernel<<<NN * 64 / 256, 256, 0, stream>>>(x, xhi, xlo);
    prep_w_kernel<<<dim3(128, 3), 256, 0, stream>>>(cw, qw, kw, cwhi, cwlo, qwf, kwf);

    conv1_mfma_kernel<<<dim3(NN / 128, 4), 256, 0, stream>>>(x, cwhi, cwlo, xhi, xlo, cb, x5o, x5frag);
    convqk_mfma_kernel<<<dim3(NN / 128, 4, 2), 256, 0, stream>>>(qwf, kwf, qb, kb, x5frag, qfrag, kfrag);

    scores_mfma_kernel<<<dim3(NN / 128, BB * 3), 256, 0, stream>>>(qfrag, kfrag, maxv3);

    topk_kernel<<<BB, HWW, 0, stream>>>(maxv3, cand);
    refine_q_kernel<<<dim3(8, 64), 256, 0, stream>>>(x5o, qw, qb, cand, q_all);
    refine_u2_kernel<<<dim3(2, 64), 256, 0, stream>>>(kw, kb, q_all, u_all, qkbg);
    refine_max_kernel<<<dim3(BB, 4, 9), 256, 0, stream>>>(x5o, u_all, maxex9);
    mask_kernel<<<BB, HWW, 0, stream>>>(maxex9, qkbg, cand, maskout, chosenidx);

    norm_kernel<<<dim3(9, BB), 256, 0, stream>>>(x5o, invb);
    seeds_direct_kernel<<<BB, 512, 0, stream>>>(x5o, invb, chosenidx, seeds);
    corr_kernel<<<dim3(9, BB), 256, 0, stream>>>(x5o, invb, seeds, corr);
    cormap_kernel<<<BB, HWW, 0, stream>>>(corr, cmap);
    proto_kernel<<<CC, 256, 0, stream>>>(x5o, cmap, proto1);
    final_kernel<<<dim3(CC, BB), 192, 0, stream>>>(x5o, proto1, cmap, out3);
}